// Round 1
// baseline (770.949 us; speedup 1.0000x reference)
//
#include <hip/hip_runtime.h>

#define IS2 0.70710678118654752440f   // np.float32(1/sqrt(2))

__device__ __forceinline__ int refl(int i, int n) {
    if (i < 0) i = -1 - i;
    if (i >= n) i = 2 * n - 1 - i;
    return i;
}

__device__ __forceinline__ float smag(float re, float im) {
    return sqrtf(re * re + im * im + 1.0e-4f) - 0.01f;
}

// q2c magnitudes: y (2x2 quad) -> (mA, mB) = orients (a-d,b+c), (a+d,b-c)
__device__ __forceinline__ void mag2(const float y[2][2], float* mA, float* mB) {
    float a = y[0][0] * IS2, b = y[0][1] * IS2;
    float c = y[1][0] * IS2, d = y[1][1] * IS2;
    *mA = smag(a - d, b + c);
    *mB = smag(a + d, b - c);
}

// ---------------------------------------------------------------------------
// fwd_j1: rowfilter(h0/h1) -> colfilter(h0/h1) -> q2c -> mag  (+ ll raw or pooled)
// MODE 0: level-1 on x:   write ll (raw, N x N) to ll_out, mags to p buffer
//         p layout: (B, 6, CH, N/2, N/2) flattened == (B, 6*CH, N/2, N/2)
// MODE 1: level-2 on p:   CH==18 (pchan = o1*3+c). mags -> Z groups 13+o2*6+o1,
//         avgpool2(ll) -> Z groups 1+o1. (ll_out unused)
// Tile: 64x64 output pixels per block, halo 3.
// ---------------------------------------------------------------------------
template <int MODE>
__global__ __launch_bounds__(256)
void fwd_j1_kernel(const float* __restrict__ in,
                   const float* __restrict__ h0,
                   const float* __restrict__ h1,
                   float* __restrict__ ll_out,
                   float* __restrict__ mag_out,
                   int CH, int N)
{
    const int img = blockIdx.z;
    const int b   = img / CH;
    const int chn = img % CH;
    const int ty0 = blockIdx.y * 64;
    const int tx0 = blockIdx.x * 64;
    const int tid = threadIdx.x;

    __shared__ float sx[70][72];
    __shared__ float slo[70][64];
    __shared__ float shi[70][64];

    float f0[5], f1[7];
#pragma unroll
    for (int t = 0; t < 5; ++t) f0[t] = h0[t];
#pragma unroll
    for (int t = 0; t < 7; ++t) f1[t] = h1[t];

    const float* src = in + (size_t)img * N * N;

    // ---- load input tile with halo 3 (70x70), reflect at borders ----
    for (int e = tid; e < 70 * 70; e += 256) {
        int rr = e / 70, cc = e % 70;
        int gr = refl(ty0 - 3 + rr, N);
        int gc = refl(tx0 - 3 + cc, N);
        sx[rr][cc] = src[(size_t)gr * N + gc];
    }
    __syncthreads();

    // ---- row convs: lo (5-tap h0), hi (7-tap h1); keep row halo for col pass ----
    for (int e = tid; e < 70 * 64; e += 256) {
        int rr = e >> 6, j = e & 63;
        float lo = 0.f, hi = 0.f;
#pragma unroll
        for (int t = 0; t < 5; ++t) lo += sx[rr][j + 1 + t] * f0[t];  // cols j-2..j+2
#pragma unroll
        for (int t = 0; t < 7; ++t) hi += sx[rr][j + t] * f1[t];      // cols j-3..j+3
        slo[rr][j] = lo;
        shi[rr][j] = hi;
    }
    __syncthreads();

    // ---- col convs per 2x2 quad + q2c + magnitudes ----
    const int Nh = N >> 1;
    for (int e = tid; e < 32 * 32; e += 256) {
        int qi = e >> 5, qj = e & 31;
        float ll4[2][2], lh4[2][2], hl4[2][2], hh4[2][2];
#pragma unroll
        for (int di = 0; di < 2; ++di) {
#pragma unroll
            for (int dj = 0; dj < 2; ++dj) {
                int i = 2 * qi + di, j = 2 * qj + dj;
                float vll = 0.f, vlh = 0.f, vhl = 0.f, vhh = 0.f;
#pragma unroll
                for (int t = 0; t < 5; ++t) {
                    vll += slo[i + 1 + t][j] * f0[t];
                    vhl += shi[i + 1 + t][j] * f0[t];
                }
#pragma unroll
                for (int t = 0; t < 7; ++t) {
                    vlh += slo[i + t][j] * f1[t];
                    vhh += shi[i + t][j] * f1[t];
                }
                ll4[di][dj] = vll; lh4[di][dj] = vlh;
                hl4[di][dj] = vhl; hh4[di][dj] = vhh;
            }
        }

        const int qy = (ty0 >> 1) + qi;
        const int qx = (tx0 >> 1) + qj;

        float m[6];
        mag2(lh4, &m[0], &m[5]);
        mag2(hh4, &m[1], &m[4]);
        mag2(hl4, &m[2], &m[3]);

        if (MODE == 0) {
            // ll raw (N x N)
            float* lptr = ll_out + (size_t)img * N * N;
            *(float2*)(lptr + (size_t)(ty0 + 2 * qi) * N + tx0 + 2 * qj) =
                make_float2(ll4[0][0], ll4[0][1]);
            *(float2*)(lptr + (size_t)(ty0 + 2 * qi + 1) * N + tx0 + 2 * qj) =
                make_float2(ll4[1][0], ll4[1][1]);
            // mags into p: (B, 6, CH, Nh, Nh)
#pragma unroll
            for (int o = 0; o < 6; ++o) {
                mag_out[(((size_t)b * 6 + o) * CH + chn) * (size_t)(Nh * Nh)
                        + (size_t)qy * Nh + qx] = m[o];
            }
        } else {
            // CH == 18: pchan = o1*3 + c
            const int o1 = chn / 3, c = chn % 3;
            float* Zb = mag_out + (size_t)b * 147 * 16384 + (size_t)qy * 128 + qx;
            // s2: group 13 + o2*6 + o1
#pragma unroll
            for (int o2 = 0; o2 < 6; ++o2) {
                Zb[(size_t)((13 + o2 * 6 + o1) * 3 + c) * 16384] = m[o2];
            }
            // s1_j1 = avgpool2(ll): group 1 + o1
            float pll = 0.25f * (ll4[0][0] + ll4[0][1] + ll4[1][0] + ll4[1][1]);
            Zb[(size_t)((1 + o1) * 3 + c) * 16384] = pll;
        }
    }
}

// ---------------------------------------------------------------------------
// fwd_j2plus fused: rowdfilt -> coldfilt -> q2c -> mag -> Z[s1_j2], avgpool -> Z[s0]
// Input: ll (B*3, 512, 512). Output tile: 32x32 in the 256x256 "ll2" space
// (i.e. 16x16 quads). Requires x rows/cols [2r0-8, 2r0+71] (80 wide), reflect.
//   rowdfilt(X, h0b, h0a, lo):  col 2j  : sum_t X[4j+2t-8]*h0b[t]
//                               col 2j+1: sum_t X[4j+2t-7]*h0a[t]
//   rowdfilt(X, h1b, h1a, hi):  col 2j  : sum_t X[4j+2t-7]*h1a[t]
//                               col 2j+1: sum_t X[4j+2t-8]*h1b[t]
//   coldfilt rows: same pattern on rows of lo/hi.
// ---------------------------------------------------------------------------
__global__ __launch_bounds__(256)
void fwd_j2_kernel(const float* __restrict__ ll,
                   const float* __restrict__ h0a, const float* __restrict__ h0b,
                   const float* __restrict__ h1a, const float* __restrict__ h1b,
                   float* __restrict__ Z)
{
    const int img = blockIdx.z;            // b*3 + c
    const int b = img / 3, c = img % 3;
    const int r0 = blockIdx.y * 32;        // origin in 256-space rows
    const int c0 = blockIdx.x * 32;        // origin in 256-space cols
    const int tid = threadIdx.x;

    __shared__ float sx[80][84];
    __shared__ float slo[80][32];
    __shared__ float shi[80][32];

    float fa0[10], fb0[10], fa1[10], fb1[10];
#pragma unroll
    for (int t = 0; t < 10; ++t) {
        fa0[t] = h0a[t]; fb0[t] = h0b[t];
        fa1[t] = h1a[t]; fb1[t] = h1b[t];
    }

    const float* src = ll + (size_t)img * 512 * 512;

    // ---- load 80x80 x-tile (rows/cols 2r0-8 .. 2r0+71), reflect ----
    for (int e = tid; e < 80 * 80; e += 256) {
        int rr = e / 80, cc = e % 80;
        int gr = refl(2 * r0 - 8 + rr, 512);
        int gc = refl(2 * c0 - 8 + cc, 512);
        sx[rr][cc] = src[(size_t)gr * 512 + gc];
    }
    __syncthreads();

    // ---- row pass (rowdfilt): produce lo/hi for 80 rows x 32 tile-cols ----
    {
        const int jj  = tid & 31;          // tile col (fixed per thread)
        const int odd = jj & 1;
        const int base = 2 * (jj & ~1);    // sx col of x index 4j-8 (+8 halo)
        float hlo[10], hhi[10];
#pragma unroll
        for (int t = 0; t < 10; ++t) {
            hlo[t] = odd ? fa0[t] : fb0[t];   // odd col -> h0a, even -> h0b
            hhi[t] = odd ? fb1[t] : fa1[t];   // odd col -> h1b, even -> h1a
        }
        const int offlo = base + odd;
        const int offhi = base + 1 - odd;
        for (int rr = tid >> 5; rr < 80; rr += 8) {
            float lo = 0.f, hi = 0.f;
#pragma unroll
            for (int t = 0; t < 10; ++t) {
                lo += sx[rr][offlo + 2 * t] * hlo[t];
                hi += sx[rr][offhi + 2 * t] * hhi[t];
            }
            slo[rr][jj] = lo;
            shi[rr][jj] = hi;
        }
    }
    __syncthreads();

    // ---- col pass (coldfilt) : one quad per thread (16x16 quads) ----
    const int qi = tid >> 4, qj = tid & 15;
    float ll2[2][2], lh4[2][2], hl4[2][2], hh4[2][2];
#pragma unroll
    for (int dj = 0; dj < 2; ++dj) {
        const int col = 2 * qj + dj;
        const int rb  = 4 * qi;
        float vll0 = 0.f, vll1 = 0.f, vlh0 = 0.f, vlh1 = 0.f;
        float vhl0 = 0.f, vhl1 = 0.f, vhh0 = 0.f, vhh1 = 0.f;
#pragma unroll
        for (int t = 0; t < 10; ++t) {
            float e0 = slo[rb + 2 * t][col];
            float e1 = slo[rb + 2 * t + 1][col];
            float g0 = shi[rb + 2 * t][col];
            float g1 = shi[rb + 2 * t + 1][col];
            vll0 += e0 * fb0[t];   // row 2i   : h0b
            vll1 += e1 * fa0[t];   // row 2i+1 : h0a
            vlh0 += e1 * fa1[t];   // row 2i   : h1a (highpass swaps)
            vlh1 += e0 * fb1[t];   // row 2i+1 : h1b
            vhl0 += g0 * fb0[t];
            vhl1 += g1 * fa0[t];
            vhh0 += g1 * fa1[t];
            vhh1 += g0 * fb1[t];
        }
        ll2[0][dj] = vll0; ll2[1][dj] = vll1;
        lh4[0][dj] = vlh0; lh4[1][dj] = vlh1;
        hl4[0][dj] = vhl0; hl4[1][dj] = vhl1;
        hh4[0][dj] = vhh0; hh4[1][dj] = vhh1;
    }

    const int qy = (r0 >> 1) + qi;
    const int qx = (c0 >> 1) + qj;
    float* Zb = Z + (size_t)b * 147 * 16384 + (size_t)qy * 128 + qx;

    // s0 = avgpool2(ll2), group 0
    Zb[(size_t)c * 16384] =
        0.25f * (ll2[0][0] + ll2[0][1] + ll2[1][0] + ll2[1][1]);

    // s1_j2: groups 7+o
    float m[6];
    mag2(lh4, &m[0], &m[5]);
    mag2(hh4, &m[1], &m[4]);
    mag2(hl4, &m[2], &m[3]);
#pragma unroll
    for (int o = 0; o < 6; ++o) {
        Zb[(size_t)((7 + o) * 3 + c) * 16384] = m[o];
    }
}

extern "C" void kernel_launch(void* const* d_in, const int* in_sizes, int n_in,
                              void* d_out, int out_size, void* d_ws, size_t ws_size,
                              hipStream_t stream)
{
    const float* x   = (const float*)d_in[0];
    const float* h0o = (const float*)d_in[1];
    const float* h1o = (const float*)d_in[2];
    const float* h0a = (const float*)d_in[3];
    const float* h0b = (const float*)d_in[4];
    const float* h1a = (const float*)d_in[5];
    const float* h1b = (const float*)d_in[6];
    float* Z = (float*)d_out;

    float* ws_ll = (float*)d_ws;                          // (32,3,512,512)
    float* ws_p  = ws_ll + (size_t)32 * 3 * 512 * 512;    // (32,18,256,256)

    dim3 blk(256);
    // level 1 on x -> ll + p
    fwd_j1_kernel<0><<<dim3(8, 8, 96), blk, 0, stream>>>(x, h0o, h1o, ws_ll, ws_p, 3, 512);
    // level 2 (decimating) on ll -> Z[s0], Z[s1_j2]
    fwd_j2_kernel<<<dim3(8, 8, 96), blk, 0, stream>>>(ws_ll, h0a, h0b, h1a, h1b, Z);
    // level-1 transform on p -> Z[s1_j1 pooled], Z[s2]
    fwd_j1_kernel<1><<<dim3(4, 4, 576), blk, 0, stream>>>(ws_p, h0o, h1o, nullptr, Z, 18, 256);
}

// Round 2
// 631.007 us; speedup vs baseline: 1.2218x; 1.2218x over previous
//
#include <hip/hip_runtime.h>

#define IS2 0.70710678118654752440f   // np.float32(1/sqrt(2))

__device__ __forceinline__ int refl(int i, int n) {
    if (i < 0) i = -1 - i;
    if (i >= n) i = 2 * n - 1 - i;
    return i;
}

__device__ __forceinline__ float smag(float re, float im) {
    return sqrtf(re * re + im * im + 1.0e-4f) - 0.01f;
}

// q2c magnitudes: y (2x2 quad) -> (mA, mB) = orients (a-d,b+c), (a+d,b-c)
__device__ __forceinline__ void mag2(const float y[2][2], float* mA, float* mB) {
    float a = y[0][0] * IS2, b = y[0][1] * IS2;
    float c = y[1][0] * IS2, d = y[1][1] * IS2;
    *mA = smag(a - d, b + c);
    *mB = smag(a + d, b - c);
}

// ---------------------------------------------------------------------------
// fwd_j1: rowfilter(h0/h1) -> colfilter(h0/h1) -> q2c -> mag  (+ ll raw or pooled)
// MODE 0: level-1 on x:   write ll (raw, N x N) to ll_out, mags to p buffer
// MODE 1: level-2 on p:   CH==18 (pchan = o1*3+c). mags -> Z groups 13+o2*6+o1,
//         avgpool2(ll) -> Z groups 1+o1.
// Tile: 64x64 output pixels per block, halo 3.
// LDS reuse: sx (70x72) is overwritten with the row-filtered hi plane (70x64,
// flat) after a barrier; lo goes to a dedicated buffer. 38.1 KB total ->
// 4 blocks/CU (vs 56.3 KB -> 2 blocks/CU before).
// ---------------------------------------------------------------------------
template <int MODE>
__global__ __launch_bounds__(256, 4)
void fwd_j1_kernel(const float* __restrict__ in,
                   const float* __restrict__ h0,
                   const float* __restrict__ h1,
                   float* __restrict__ ll_out,
                   float* __restrict__ mag_out,
                   int CH, int N)
{
    const int img = blockIdx.z;
    const int b   = img / CH;
    const int chn = img % CH;
    const int ty0 = blockIdx.y * 64;
    const int tx0 = blockIdx.x * 64;
    const int tid = threadIdx.x;

    __shared__ float sx[70 * 72];   // input tile, then reused as shi (70*64 flat)
    __shared__ float slo[70 * 64];

    float f0[5], f1[7];
#pragma unroll
    for (int t = 0; t < 5; ++t) f0[t] = h0[t];
#pragma unroll
    for (int t = 0; t < 7; ++t) f1[t] = h1[t];

    const float* src = in + (size_t)img * N * N;

    // ---- load input tile with halo 3 (70x70), reflect at borders ----
    for (int e = tid; e < 70 * 70; e += 256) {
        int rr = e / 70, cc = e % 70;
        int gr = refl(ty0 - 3 + rr, N);
        int gc = refl(tx0 - 3 + cc, N);
        sx[rr * 72 + cc] = src[(size_t)gr * N + gc];
    }
    __syncthreads();

    // ---- row convs into registers (fixed trip count -> stays in VGPRs) ----
    float vlo[18], vhi[18];
#pragma unroll
    for (int k = 0; k < 18; ++k) {
        int e = tid + k * 256;
        if (e < 70 * 64) {
            int rr = e >> 6, j = e & 63;
            const float* row = &sx[rr * 72];
            float lo = 0.f, hi = 0.f;
#pragma unroll
            for (int t = 0; t < 5; ++t) lo += row[j + 1 + t] * f0[t];  // cols j-2..j+2
#pragma unroll
            for (int t = 0; t < 7; ++t) hi += row[j + t] * f1[t];      // cols j-3..j+3
            vlo[k] = lo; vhi[k] = hi;
        }
    }
    __syncthreads();   // all reads of sx complete
#pragma unroll
    for (int k = 0; k < 18; ++k) {
        int e = tid + k * 256;
        if (e < 70 * 64) {
            slo[e] = vlo[k];
            sx[e]  = vhi[k];   // shi lives where the input tile was
        }
    }
    __syncthreads();

    // ---- col convs per 2x2 quad + q2c + magnitudes ----
    const int Nh = N >> 1;
    for (int e = tid; e < 32 * 32; e += 256) {
        int qi = e >> 5, qj = e & 31;
        float ll4[2][2], lh4[2][2], hl4[2][2], hh4[2][2];
#pragma unroll
        for (int di = 0; di < 2; ++di) {
#pragma unroll
            for (int dj = 0; dj < 2; ++dj) {
                int i = 2 * qi + di, j = 2 * qj + dj;
                float vll = 0.f, vlh = 0.f, vhl = 0.f, vhh = 0.f;
#pragma unroll
                for (int t = 0; t < 5; ++t) {
                    vll += slo[(i + 1 + t) * 64 + j] * f0[t];
                    vhl += sx [(i + 1 + t) * 64 + j] * f0[t];
                }
#pragma unroll
                for (int t = 0; t < 7; ++t) {
                    vlh += slo[(i + t) * 64 + j] * f1[t];
                    vhh += sx [(i + t) * 64 + j] * f1[t];
                }
                ll4[di][dj] = vll; lh4[di][dj] = vlh;
                hl4[di][dj] = vhl; hh4[di][dj] = vhh;
            }
        }

        const int qy = (ty0 >> 1) + qi;
        const int qx = (tx0 >> 1) + qj;

        float m[6];
        mag2(lh4, &m[0], &m[5]);
        mag2(hh4, &m[1], &m[4]);
        mag2(hl4, &m[2], &m[3]);

        if (MODE == 0) {
            float* lptr = ll_out + (size_t)img * N * N;
            *(float2*)(lptr + (size_t)(ty0 + 2 * qi) * N + tx0 + 2 * qj) =
                make_float2(ll4[0][0], ll4[0][1]);
            *(float2*)(lptr + (size_t)(ty0 + 2 * qi + 1) * N + tx0 + 2 * qj) =
                make_float2(ll4[1][0], ll4[1][1]);
#pragma unroll
            for (int o = 0; o < 6; ++o) {
                mag_out[(((size_t)b * 6 + o) * CH + chn) * (size_t)(Nh * Nh)
                        + (size_t)qy * Nh + qx] = m[o];
            }
        } else {
            const int o1 = chn / 3, c = chn % 3;
            float* Zb = mag_out + (size_t)b * 147 * 16384 + (size_t)qy * 128 + qx;
#pragma unroll
            for (int o2 = 0; o2 < 6; ++o2) {
                Zb[(size_t)((13 + o2 * 6 + o1) * 3 + c) * 16384] = m[o2];
            }
            float pll = 0.25f * (ll4[0][0] + ll4[0][1] + ll4[1][0] + ll4[1][1]);
            Zb[(size_t)((1 + o1) * 3 + c) * 16384] = pll;
        }
    }
}

// ---------------------------------------------------------------------------
// fwd_j2plus fused: rowdfilt -> coldfilt -> q2c -> mag -> Z[s1_j2], avgpool -> Z[s0]
// Input: ll (B*3, 512, 512). Output tile: 32x32 in the 256x256 "ll2" space.
// LDS reuse: sx (80x84) overwritten after the row pass with slo/shi (stride 33
// to spread banks). 26.9 KB total -> 6 blocks/CU.
// ---------------------------------------------------------------------------
__global__ __launch_bounds__(256, 4)
void fwd_j2_kernel(const float* __restrict__ ll,
                   const float* __restrict__ h0a, const float* __restrict__ h0b,
                   const float* __restrict__ h1a, const float* __restrict__ h1b,
                   float* __restrict__ Z)
{
    const int img = blockIdx.z;            // b*3 + c
    const int b = img / 3, c = img % 3;
    const int r0 = blockIdx.y * 32;        // origin in 256-space rows
    const int c0 = blockIdx.x * 32;        // origin in 256-space cols
    const int tid = threadIdx.x;

    __shared__ float sx[80 * 84];          // input tile, then slo/shi (stride 33)
    float* const sloP = sx;                // [80][33] flat, max 2638
    float* const shiP = sx + 2688;         // [80][33] flat, max 2688+2638=5326 < 6720

    float fa0[10], fb0[10], fa1[10], fb1[10];
#pragma unroll
    for (int t = 0; t < 10; ++t) {
        fa0[t] = h0a[t]; fb0[t] = h0b[t];
        fa1[t] = h1a[t]; fb1[t] = h1b[t];
    }

    const float* src = ll + (size_t)img * 512 * 512;

    // ---- load 80x80 x-tile (rows/cols 2r0-8 .. 2r0+71), reflect ----
    for (int e = tid; e < 80 * 80; e += 256) {
        int rr = e / 80, cc = e % 80;
        int gr = refl(2 * r0 - 8 + rr, 512);
        int gc = refl(2 * c0 - 8 + cc, 512);
        sx[rr * 84 + cc] = src[(size_t)gr * 512 + gc];
    }
    __syncthreads();

    // ---- row pass (rowdfilt) into registers ----
    const int jj  = tid & 31;          // tile col (fixed per thread)
    const int odd = jj & 1;
    const int base = 2 * (jj & ~1);    // sx col of x index 4j-8 (+8 halo)
    float hlo[10], hhi[10];
#pragma unroll
    for (int t = 0; t < 10; ++t) {
        hlo[t] = odd ? fa0[t] : fb0[t];   // odd col -> h0a, even -> h0b
        hhi[t] = odd ? fb1[t] : fa1[t];   // odd col -> h1b, even -> h1a
    }
    const int offlo = base + odd;
    const int offhi = base + 1 - odd;
    float rlo[10], rhi[10];
#pragma unroll
    for (int k = 0; k < 10; ++k) {
        int rr = (tid >> 5) + 8 * k;
        const float* row = &sx[rr * 84];
        float lo = 0.f, hi = 0.f;
#pragma unroll
        for (int t = 0; t < 10; ++t) {
            lo += row[offlo + 2 * t] * hlo[t];
            hi += row[offhi + 2 * t] * hhi[t];
        }
        rlo[k] = lo; rhi[k] = hi;
    }
    __syncthreads();   // all reads of sx complete
#pragma unroll
    for (int k = 0; k < 10; ++k) {
        int rr = (tid >> 5) + 8 * k;
        sloP[rr * 33 + jj] = rlo[k];
        shiP[rr * 33 + jj] = rhi[k];
    }
    __syncthreads();

    // ---- col pass (coldfilt) : one quad per thread (16x16 quads) ----
    const int qi = tid >> 4, qj = tid & 15;
    float ll2[2][2], lh4[2][2], hl4[2][2], hh4[2][2];
#pragma unroll
    for (int dj = 0; dj < 2; ++dj) {
        const int col = 2 * qj + dj;
        const int rb  = 4 * qi;
        float vll0 = 0.f, vll1 = 0.f, vlh0 = 0.f, vlh1 = 0.f;
        float vhl0 = 0.f, vhl1 = 0.f, vhh0 = 0.f, vhh1 = 0.f;
#pragma unroll
        for (int t = 0; t < 10; ++t) {
            float e0 = sloP[(rb + 2 * t) * 33 + col];
            float e1 = sloP[(rb + 2 * t + 1) * 33 + col];
            float g0 = shiP[(rb + 2 * t) * 33 + col];
            float g1 = shiP[(rb + 2 * t + 1) * 33 + col];
            vll0 += e0 * fb0[t];   // row 2i   : h0b
            vll1 += e1 * fa0[t];   // row 2i+1 : h0a
            vlh0 += e1 * fa1[t];   // row 2i   : h1a (highpass swaps)
            vlh1 += e0 * fb1[t];   // row 2i+1 : h1b
            vhl0 += g0 * fb0[t];
            vhl1 += g1 * fa0[t];
            vhh0 += g1 * fa1[t];
            vhh1 += g0 * fb1[t];
        }
        ll2[0][dj] = vll0; ll2[1][dj] = vll1;
        lh4[0][dj] = vlh0; lh4[1][dj] = vlh1;
        hl4[0][dj] = vhl0; hl4[1][dj] = vhl1;
        hh4[0][dj] = vhh0; hh4[1][dj] = vhh1;
    }

    const int qy = (r0 >> 1) + qi;
    const int qx = (c0 >> 1) + qj;
    float* Zb = Z + (size_t)b * 147 * 16384 + (size_t)qy * 128 + qx;

    // s0 = avgpool2(ll2), group 0
    Zb[(size_t)c * 16384] =
        0.25f * (ll2[0][0] + ll2[0][1] + ll2[1][0] + ll2[1][1]);

    // s1_j2: groups 7+o
    float m[6];
    mag2(lh4, &m[0], &m[5]);
    mag2(hh4, &m[1], &m[4]);
    mag2(hl4, &m[2], &m[3]);
#pragma unroll
    for (int o = 0; o < 6; ++o) {
        Zb[(size_t)((7 + o) * 3 + c) * 16384] = m[o];
    }
}

extern "C" void kernel_launch(void* const* d_in, const int* in_sizes, int n_in,
                              void* d_out, int out_size, void* d_ws, size_t ws_size,
                              hipStream_t stream)
{
    const float* x   = (const float*)d_in[0];
    const float* h0o = (const float*)d_in[1];
    const float* h1o = (const float*)d_in[2];
    const float* h0a = (const float*)d_in[3];
    const float* h0b = (const float*)d_in[4];
    const float* h1a = (const float*)d_in[5];
    const float* h1b = (const float*)d_in[6];
    float* Z = (float*)d_out;

    float* ws_ll = (float*)d_ws;                          // (32,3,512,512)
    float* ws_p  = ws_ll + (size_t)32 * 3 * 512 * 512;    // (32,18,256,256)

    dim3 blk(256);
    // level 1 on x -> ll + p
    fwd_j1_kernel<0><<<dim3(8, 8, 96), blk, 0, stream>>>(x, h0o, h1o, ws_ll, ws_p, 3, 512);
    // level 2 (decimating) on ll -> Z[s0], Z[s1_j2]
    fwd_j2_kernel<<<dim3(8, 8, 96), blk, 0, stream>>>(ws_ll, h0a, h0b, h1a, h1b, Z);
    // level-1 transform on p -> Z[s1_j1 pooled], Z[s2]
    fwd_j1_kernel<1><<<dim3(4, 4, 576), blk, 0, stream>>>(ws_p, h0o, h1o, nullptr, Z, 18, 256);
}